// Round 1
// baseline (272.439 us; speedup 1.0000x reference)
//
#include <hip/hip_runtime.h>

// Problem constants (from reference setup_inputs)
#define B    128
#define H    14
#define W    14
#define C    512
#define NCLS 200
#define HW   (H * W)          // 196
#define TP_DIM 15             // t_p is [15,15,14,14]
#define SENT_OFF ((14 * TP_DIM + 14) * HW)  // sentinel template row offset

typedef float  v4f __attribute__((ext_vector_type(4)));
typedef int    v4i __attribute__((ext_vector_type(4)));

// ---------------------------------------------------------------------------
// Kernel A: argmax producer.
//   Grid 256 blocks x 512 threads. Block (2b+half) owns batch b, channels
//   [half*256, half*256+256). Thread (sl, cg): channels c0..c0+3 (v4f loads),
//   spatial slice sl*25..(+25|+21). LDS combine over the 8 slices in
//   ascending order with strict '>' preserves jnp.argmax first-occurrence
//   semantics. Writes t_p row offsets (ws_off[B*C]) and class id (ws_cls[B]).
//   Reads x exactly once (51.4 MB total, no redundancy) and leaves it L3-hot
//   for kernel B.
// ---------------------------------------------------------------------------
__global__ __launch_bounds__(512) void argmax_kernel(
        const float* __restrict__ x,
        const float* __restrict__ gt,
        int* __restrict__ ws_off,
        int* __restrict__ ws_cls) {
    __shared__ v4f s_best[8][64];
    __shared__ v4i s_idx[8][64];

    const int tid  = threadIdx.x;
    const int b    = blockIdx.x >> 1;
    const int half = blockIdx.x & 1;
    const int cg   = tid & 63;        // channel group within half (64 x 4ch)
    const int sl   = tid >> 6;        // spatial slice 0..7 (== wave id)
    const int c0   = half * 256 + cg * 4;

    const int sbeg = sl * 25;
    const int scnt = (sl == 7) ? (HW - 7 * 25) : 25;   // 21 for last slice

    const float* __restrict__ xp = x + (size_t)b * HW * C + c0;

    v4f best = *(const v4f*)(xp + (size_t)sbeg * C);
    v4i bidx = (v4i){sbeg, sbeg, sbeg, sbeg};
#pragma unroll 4
    for (int k = 1; k < scnt; ++k) {
        const int s = sbeg + k;
        v4f v = *(const v4f*)(xp + (size_t)s * C);
        if (v.x > best.x) { best.x = v.x; bidx.x = s; }  // strict > = first occ.
        if (v.y > best.y) { best.y = v.y; bidx.y = s; }
        if (v.z > best.z) { best.z = v.z; bidx.z = s; }
        if (v.w > best.w) { best.w = v.w; bidx.w = s; }
    }
    s_best[sl][cg] = best;
    s_idx[sl][cg]  = bidx;
    __syncthreads();

    if (tid < 64) {
        // combine 8 slices in ascending-s order: strict '>' keeps earliest s
        v4f cb = s_best[0][tid];
        v4i ci = s_idx[0][tid];
#pragma unroll
        for (int k = 1; k < 8; ++k) {
            v4f p = s_best[k][tid];
            v4i q = s_idx[k][tid];
            if (p.x > cb.x) { cb.x = p.x; ci.x = q.x; }
            if (p.y > cb.y) { cb.y = p.y; ci.y = q.y; }
            if (p.z > cb.z) { cb.z = p.z; ci.z = q.z; }
            if (p.w > cb.w) { cb.w = p.w; ci.w = q.w; }
        }
        v4i o;
        o.x = (cb.x == 0.0f) ? SENT_OFF : ((ci.x / W) * TP_DIM + (ci.x % W)) * HW;
        o.y = (cb.y == 0.0f) ? SENT_OFF : ((ci.y / W) * TP_DIM + (ci.y % W)) * HW;
        o.z = (cb.z == 0.0f) ? SENT_OFF : ((ci.z / W) * TP_DIM + (ci.z % W)) * HW;
        o.w = (cb.w == 0.0f) ? SENT_OFF : ((ci.w / W) * TP_DIM + (ci.w % W)) * HW;
        *(v4i*)(ws_off + (size_t)b * C + half * 256 + tid * 4) = o;
    } else if (half == 0 && tid < 128) {
        // class argmax over gt[b], wave 1, index-min tie-break
        const int lane = tid - 64;
        const float* __restrict__ g = gt + (size_t)b * NCLS;
        float gb = -__builtin_inff();
        int   gi = NCLS;
        for (int i = lane; i < NCLS; i += 64) {   // ascending per lane
            float v = g[i];
            if (v > gb) { gb = v; gi = i; }       // keeps smallest index
        }
#pragma unroll
        for (int d = 1; d < 64; d <<= 1) {
            float ov = __shfl_xor(gb, d);
            int   oi = __shfl_xor(gi, d);
            if (ov > gb || (ov == gb && oi < gi)) { gb = ov; gi = oi; }
        }
        if (lane == 0) ws_cls[b] = gi;
    }
}

// ---------------------------------------------------------------------------
// Kernel B: streaming consumer.
//   Grid 1024 blocks x 256 threads = 4 blocks/CU, 16 waves/CU.
//   b = blockIdx & 127 -> all 8 chunks of a batch share blockIdx mod 8,
//   i.e. the same XCD (round-robin dispatch) for x / ctpl L2 locality.
//   Unit = 4 spatial x 4 channels: one v4i offset load (L2, 256 KB table),
//   four 16-B t_p gathers (L2, 176 KB table), v4f x/ctpl loads, 12 v4f
//   nontemporal stores.
// ---------------------------------------------------------------------------
__global__ __launch_bounds__(256) void stream_kernel(
        const float* __restrict__ x,
        const float* __restrict__ t_p,
        const float* __restrict__ ctpl,
        const int*   __restrict__ ws_off,
        const int*   __restrict__ ws_cls,
        float*       __restrict__ out) {
    const int b     = blockIdx.x & 127;
    const int chunk = blockIdx.x >> 7;      // 0..7
    const int cls   = ws_cls[b];            // uniform per block

    const size_t plane = (size_t)B * HW * C;
    const int*   __restrict__ offp = ws_off + (size_t)b * C;
    const float* __restrict__ ctp  = ctpl + (size_t)cls * HW * C;

    // units per batch: 49 quads x 128 channel-groups = 6272
    for (int t = chunk * 256 + (int)threadIdx.x; t < 49 * 128; t += 2048) {
        const int q  = t >> 7;        // spatial quad 0..48 (uniform per wave)
        const int cg = t & 127;
        const int s0 = q * 4;
        const int c0 = cg * 4;

        v4i off = *(const v4i*)(offp + c0);

        // one aligned 16-B gather per channel (t_p row offsets are x4 floats)
        v4f t0 = *(const v4f*)(t_p + off.x + s0);
        v4f t1 = *(const v4f*)(t_p + off.y + s0);
        v4f t2 = *(const v4f*)(t_p + off.z + s0);
        v4f t3 = *(const v4f*)(t_p + off.w + s0);
        v4f tv[4];
        tv[0] = (v4f){t0.x, t1.x, t2.x, t3.x};
        tv[1] = (v4f){t0.y, t1.y, t2.y, t3.y};
        tv[2] = (v4f){t0.z, t1.z, t2.z, t3.z};
        tv[3] = (v4f){t0.w, t1.w, t2.w, t3.w};

        const size_t base = ((size_t)b * HW + s0) * C + c0;
        const float* __restrict__ xp = x + base;
        const float* __restrict__ cp = ctp + (size_t)s0 * C + c0;
        float* __restrict__ out_m = out + base;
        float* __restrict__ out_x = out + plane + base;
        float* __restrict__ out_t = out + 2 * plane + base;

#pragma unroll
        for (int i = 0; i < 4; ++i) {
            v4f xv = *(const v4f*)(xp + (size_t)i * C);
            v4f ct = *(const v4f*)(cp + (size_t)i * C);
            v4f tt = tv[i];
            v4f m;
            m.x = fmaxf(xv.x * tt.x, 0.0f) * ct.x;
            m.y = fmaxf(xv.y * tt.y, 0.0f) * ct.y;
            m.z = fmaxf(xv.z * tt.z, 0.0f) * ct.z;
            m.w = fmaxf(xv.w * tt.w, 0.0f) * ct.w;
            __builtin_nontemporal_store(m,  (v4f*)(out_m + (size_t)i * C));
            __builtin_nontemporal_store(xv, (v4f*)(out_x + (size_t)i * C));
            __builtin_nontemporal_store(tt, (v4f*)(out_t + (size_t)i * C));
        }
    }
}

// ---------------------------------------------------------------------------
extern "C" void kernel_launch(void* const* d_in, const int* in_sizes, int n_in,
                              void* d_out, int out_size, void* d_ws, size_t ws_size,
                              hipStream_t stream) {
    const float* x    = (const float*)d_in[0];  // [B,H,W,C]
    const float* gt   = (const float*)d_in[1];  // [B,NCLS]
    const float* t_p  = (const float*)d_in[2];  // [15,15,H,W]
    const float* ctpl = (const float*)d_in[3];  // [NCLS,H,W,C]
    float* out = (float*)d_out;                 // [3, B,H,W,C] flat

    int* ws_off = (int*)d_ws;                   // [B*C] t_p row offsets
    int* ws_cls = ws_off + B * C;               // [B] class ids

    hipLaunchKernelGGL(argmax_kernel,
                       dim3(2 * B), dim3(512), 0, stream,
                       x, gt, ws_off, ws_cls);
    hipLaunchKernelGGL(stream_kernel,
                       dim3(8 * B), dim3(256), 0, stream,
                       x, t_p, ctpl, ws_off, ws_cls, out);
}

// Round 2
// 260.552 us; speedup vs baseline: 1.0456x; 1.0456x over previous
//
#include <hip/hip_runtime.h>

// Problem constants (from reference setup_inputs)
#define B    128
#define H    14
#define W    14
#define C    512
#define NCLS 200
#define HW   (H * W)          // 196
#define TP_DIM 15             // t_p is [15,15,14,14]
#define SENT_OFF ((14 * TP_DIM + 14) * HW)  // sentinel template row offset

typedef float  v4f __attribute__((ext_vector_type(4)));
typedef int    v4i __attribute__((ext_vector_type(4)));

// ---------------------------------------------------------------------------
// Single fused kernel, channel-split (no redundant work, no second launch).
// Grid = 256 blocks (2 per batch: channel halves), 512 threads.
//
//   Phase 1: block (2b+half) owns batch b, channels [half*256, +256).
//     Waves 0..6: thread (sl, cg) argmaxes spatial slice sl*28..+28 for its
//       4 channels with v4f loads (1 KB/wave-instr coalescing). 7x28 = 196.
//     Wave 7 concurrently reduces argmax(gt[b]) via shfl (index-min
//       tie-break) -> s_cls.
//     Combine: 64 threads fold the 7 slices in ascending order (strict '>'
//       preserves jnp.argmax first-occurrence) -> t_p row offsets in LDS.
//     x is read exactly once across the grid (51.4 MB) and stays L2-warm
//     on this block's own CU/XCD for phase 2.
//
//   Phase 2: same channel half, all 49 spatial quads. cg fixed per thread
//     (wave-uniform quad per iteration) so the LDS offset load is hoisted.
//     Unit = 4 spatial x 4 channels: four 16-B t_p gathers (176 KB,
//     L2-resident), v4f x/ctpl loads, 12 v4f nontemporal stores
//     ([masked | x | templates] flat).
// ---------------------------------------------------------------------------
__global__ __launch_bounds__(512) void fused_kernel(
        const float* __restrict__ x,
        const float* __restrict__ gt,
        const float* __restrict__ t_p,
        const float* __restrict__ ctpl,
        float*       __restrict__ out) {
    __shared__ v4f s_best[7][64];
    __shared__ v4i s_idx[7][64];
    __shared__ int s_off[256];
    __shared__ int s_cls;

    const int tid  = threadIdx.x;
    const int b    = blockIdx.x >> 1;
    const int half = blockIdx.x & 1;
    const int cg   = tid & 63;        // channel group (4 channels)
    const int sl   = tid >> 6;        // wave id
    const int c0   = half * 256 + cg * 4;

    const float* __restrict__ xp = x + (size_t)b * HW * C + c0;

    // ---------------- Phase 1: argmaxes ------------------------------------
    if (sl < 7) {
        // spatial slice sl*28 .. sl*28+27 for channels c0..c0+3
        const int sbeg = sl * 28;
        v4f best = *(const v4f*)(xp + (size_t)sbeg * C);
        v4i bidx = (v4i){sbeg, sbeg, sbeg, sbeg};
#pragma unroll 9
        for (int k = 1; k < 28; ++k) {
            const int s = sbeg + k;
            v4f v = *(const v4f*)(xp + (size_t)s * C);
            if (v.x > best.x) { best.x = v.x; bidx.x = s; }  // strict > = first occ.
            if (v.y > best.y) { best.y = v.y; bidx.y = s; }
            if (v.z > best.z) { best.z = v.z; bidx.z = s; }
            if (v.w > best.w) { best.w = v.w; bidx.w = s; }
        }
        s_best[sl][cg] = best;
        s_idx[sl][cg]  = bidx;
    } else {
        // wave 7: class argmax over gt[b], index-min tie-break
        const int lane = cg;
        const float* __restrict__ g = gt + (size_t)b * NCLS;
        float gb = -__builtin_inff();
        int   gi = NCLS;
        for (int i = lane; i < NCLS; i += 64) {   // ascending per lane
            float v = g[i];
            if (v > gb) { gb = v; gi = i; }       // keeps smallest index
        }
#pragma unroll
        for (int d = 1; d < 64; d <<= 1) {
            float ov = __shfl_xor(gb, d);
            int   oi = __shfl_xor(gi, d);
            if (ov > gb || (ov == gb && oi < gi)) { gb = ov; gi = oi; }
        }
        if (lane == 0) s_cls = gi;
    }
    __syncthreads();

    // ---------------- Combine: fold 7 slices, compute t_p offsets ----------
    if (tid < 64) {
        v4f cb = s_best[0][tid];
        v4i ci = s_idx[0][tid];
#pragma unroll
        for (int k = 1; k < 7; ++k) {           // ascending s: '>' keeps first
            v4f p = s_best[k][tid];
            v4i q = s_idx[k][tid];
            if (p.x > cb.x) { cb.x = p.x; ci.x = q.x; }
            if (p.y > cb.y) { cb.y = p.y; ci.y = q.y; }
            if (p.z > cb.z) { cb.z = p.z; ci.z = q.z; }
            if (p.w > cb.w) { cb.w = p.w; ci.w = q.w; }
        }
        v4i o;
        o.x = (cb.x == 0.0f) ? SENT_OFF : ((ci.x / W) * TP_DIM + (ci.x % W)) * HW;
        o.y = (cb.y == 0.0f) ? SENT_OFF : ((ci.y / W) * TP_DIM + (ci.y % W)) * HW;
        o.z = (cb.z == 0.0f) ? SENT_OFF : ((ci.z / W) * TP_DIM + (ci.z % W)) * HW;
        o.w = (cb.w == 0.0f) ? SENT_OFF : ((ci.w / W) * TP_DIM + (ci.w % W)) * HW;
        *(v4i*)&s_off[tid * 4] = o;
    }
    __syncthreads();

    // ---------------- Phase 2: elementwise streaming -----------------------
    const int klass = s_cls;
    const v4i off   = *(const v4i*)&s_off[cg * 4];   // hoisted: cg fixed

    const size_t plane = (size_t)B * HW * C;
    const float* __restrict__ ctp = ctpl + (size_t)klass * HW * C;

    // quads q = sl, sl+8, ... (< 49); wave-uniform q, 64 consecutive cg
    for (int q = sl; q < 49; q += 8) {
        const int s0 = q * 4;

        // one aligned 16-B gather per channel (t_p is 176 KB -> L2-resident)
        v4f t0 = *(const v4f*)(t_p + off.x + s0);
        v4f t1 = *(const v4f*)(t_p + off.y + s0);
        v4f t2 = *(const v4f*)(t_p + off.z + s0);
        v4f t3 = *(const v4f*)(t_p + off.w + s0);
        v4f tv[4];
        tv[0] = (v4f){t0.x, t1.x, t2.x, t3.x};
        tv[1] = (v4f){t0.y, t1.y, t2.y, t3.y};
        tv[2] = (v4f){t0.z, t1.z, t2.z, t3.z};
        tv[3] = (v4f){t0.w, t1.w, t2.w, t3.w};

        const size_t base = ((size_t)b * HW + s0) * C + c0;
        const float* __restrict__ xq = x + base;
        const float* __restrict__ cp = ctp + (size_t)s0 * C + c0;
        float* __restrict__ out_m = out + base;
        float* __restrict__ out_x = out + plane + base;
        float* __restrict__ out_t = out + 2 * plane + base;

#pragma unroll
        for (int i = 0; i < 4; ++i) {
            v4f xv = *(const v4f*)(xq + (size_t)i * C);
            v4f ct = *(const v4f*)(cp + (size_t)i * C);
            v4f tt = tv[i];
            v4f m;
            m.x = fmaxf(xv.x * tt.x, 0.0f) * ct.x;
            m.y = fmaxf(xv.y * tt.y, 0.0f) * ct.y;
            m.z = fmaxf(xv.z * tt.z, 0.0f) * ct.z;
            m.w = fmaxf(xv.w * tt.w, 0.0f) * ct.w;
            __builtin_nontemporal_store(m,  (v4f*)(out_m + (size_t)i * C));
            __builtin_nontemporal_store(xv, (v4f*)(out_x + (size_t)i * C));
            __builtin_nontemporal_store(tt, (v4f*)(out_t + (size_t)i * C));
        }
    }
}

// ---------------------------------------------------------------------------
extern "C" void kernel_launch(void* const* d_in, const int* in_sizes, int n_in,
                              void* d_out, int out_size, void* d_ws, size_t ws_size,
                              hipStream_t stream) {
    const float* x    = (const float*)d_in[0];  // [B,H,W,C]
    const float* gt   = (const float*)d_in[1];  // [B,NCLS]
    const float* t_p  = (const float*)d_in[2];  // [15,15,H,W]
    const float* ctpl = (const float*)d_in[3];  // [NCLS,H,W,C]
    float* out = (float*)d_out;                 // [3, B,H,W,C] flat

    hipLaunchKernelGGL(fused_kernel,
                       dim3(2 * B), dim3(512), 0, stream,
                       x, gt, t_p, ctpl, out);
}

// Round 3
// 260.408 us; speedup vs baseline: 1.0462x; 1.0006x over previous
//
#include <hip/hip_runtime.h>

// Problem constants (from reference setup_inputs)
#define B    128
#define H    14
#define W    14
#define C    512
#define NCLS 200
#define HW   (H * W)          // 196
#define TP_DIM 15             // t_p is [15,15,14,14]
#define SENT_OFF ((14 * TP_DIM + 14) * HW)  // sentinel template row offset

typedef float  v4f __attribute__((ext_vector_type(4)));
typedef int    v4i __attribute__((ext_vector_type(4)));

// ---------------------------------------------------------------------------
// Single fused kernel, QUARTER-channel split: 512 blocks x 512 threads
// = 2 blocks/CU, 16 waves/CU (2x round-2 occupancy; that kernel idled its
// CU during phase-1 latency + barrier with nothing co-resident).
//
//   Block (4b+q) owns batch b, channels [q*128, q*128+128). Zero redundant
//   work across blocks; x read exactly once grid-wide (51.4 MB).
//
//   Phase 1: thread (sl, cg), sl=tid>>5 in 0..13: argmax of spatial slice
//     [14*sl, 14*sl+14) for channels c0..c0+3 via 14 independent v4f loads
//     (fully unrolled -> max MLP). Wave 7 (sl=14,15) concurrently reduces
//     argmax(gt[b]) via shfl with index-min tie-break.
//     Combine: 32 threads fold the 14 slices in ascending-s order with
//     strict '>' (preserves jnp.argmax first-occurrence) -> t_p row offsets.
//
//   Phase 2: 32 cg x 16 quad-slots; q = sl, sl+16, sl+32(, 48). Unit =
//     4 spatial x 4 channels: four 16-B t_p gathers (176 KB, L2-resident),
//     v4f x/ctpl loads (512 B contiguous per 32-lane half), 12 v4f
//     nontemporal stores ([masked | x | templates] flat).
//
//   __launch_bounds__(512, 4): 4 waves/SIMD = 2 blocks/CU target, caps
//   VGPR at 128.
// ---------------------------------------------------------------------------
__global__ __launch_bounds__(512, 4) void fused_kernel(
        const float* __restrict__ x,
        const float* __restrict__ gt,
        const float* __restrict__ t_p,
        const float* __restrict__ ctpl,
        float*       __restrict__ out) {
    __shared__ v4f s_best[14][32];
    __shared__ v4i s_idx[14][32];
    __shared__ int s_off[128];
    __shared__ int s_cls;

    const int tid     = threadIdx.x;
    const int b       = blockIdx.x >> 2;
    const int quarter = blockIdx.x & 3;
    const int cg      = tid & 31;     // channel group (4 channels) 0..31
    const int sl      = tid >> 5;     // slice / quad-slot id 0..15
    const int c0      = quarter * 128 + cg * 4;

    const float* __restrict__ xp = x + (size_t)b * HW * C + c0;

    // ---------------- Phase 1: argmaxes ------------------------------------
    if (sl < 14) {
        // spatial slice 14*sl .. 14*sl+13 for channels c0..c0+3
        const int sbeg = sl * 14;
        v4f best = *(const v4f*)(xp + (size_t)sbeg * C);
        v4i bidx = (v4i){sbeg, sbeg, sbeg, sbeg};
#pragma unroll
        for (int k = 1; k < 14; ++k) {
            const int s = sbeg + k;
            v4f v = *(const v4f*)(xp + (size_t)s * C);
            if (v.x > best.x) { best.x = v.x; bidx.x = s; }  // strict > = first occ.
            if (v.y > best.y) { best.y = v.y; bidx.y = s; }
            if (v.z > best.z) { best.z = v.z; bidx.z = s; }
            if (v.w > best.w) { best.w = v.w; bidx.w = s; }
        }
        s_best[sl][cg] = best;
        s_idx[sl][cg]  = bidx;
    } else {
        // wave 7 (tid 448..511): class argmax over gt[b], index-min tie-break
        const int lane = tid - 448;
        const float* __restrict__ g = gt + (size_t)b * NCLS;
        float gb = -__builtin_inff();
        int   gi = NCLS;
        for (int i = lane; i < NCLS; i += 64) {   // ascending per lane
            float v = g[i];
            if (v > gb) { gb = v; gi = i; }       // keeps smallest index
        }
#pragma unroll
        for (int d = 1; d < 64; d <<= 1) {
            float ov = __shfl_xor(gb, d);
            int   oi = __shfl_xor(gi, d);
            if (ov > gb || (ov == gb && oi < gi)) { gb = ov; gi = oi; }
        }
        if (lane == 0) s_cls = gi;
    }
    __syncthreads();

    // ---------------- Combine: fold 14 slices, compute t_p offsets ---------
    if (tid < 32) {
        v4f cb = s_best[0][tid];
        v4i ci = s_idx[0][tid];
#pragma unroll
        for (int k = 1; k < 14; ++k) {          // ascending s: '>' keeps first
            v4f p = s_best[k][tid];
            v4i q = s_idx[k][tid];
            if (p.x > cb.x) { cb.x = p.x; ci.x = q.x; }
            if (p.y > cb.y) { cb.y = p.y; ci.y = q.y; }
            if (p.z > cb.z) { cb.z = p.z; ci.z = q.z; }
            if (p.w > cb.w) { cb.w = p.w; ci.w = q.w; }
        }
        v4i o;
        o.x = (cb.x == 0.0f) ? SENT_OFF : ((ci.x / W) * TP_DIM + (ci.x % W)) * HW;
        o.y = (cb.y == 0.0f) ? SENT_OFF : ((ci.y / W) * TP_DIM + (ci.y % W)) * HW;
        o.z = (cb.z == 0.0f) ? SENT_OFF : ((ci.z / W) * TP_DIM + (ci.z % W)) * HW;
        o.w = (cb.w == 0.0f) ? SENT_OFF : ((ci.w / W) * TP_DIM + (ci.w % W)) * HW;
        *(v4i*)&s_off[tid * 4] = o;
    }
    __syncthreads();

    // ---------------- Phase 2: elementwise streaming -----------------------
    const int klass = s_cls;
    const v4i off   = *(const v4i*)&s_off[cg * 4];   // hoisted: cg fixed

    const size_t plane = (size_t)B * HW * C;
    const float* __restrict__ ctp = ctpl + (size_t)klass * HW * C;

    // quads q = sl, sl+16, sl+32 (, 48 for sl==0); 49 quads total
    for (int q = sl; q < 49; q += 16) {
        const int s0 = q * 4;

        // one aligned 16-B gather per channel (t_p is 176 KB -> L2-resident)
        v4f t0 = *(const v4f*)(t_p + off.x + s0);
        v4f t1 = *(const v4f*)(t_p + off.y + s0);
        v4f t2 = *(const v4f*)(t_p + off.z + s0);
        v4f t3 = *(const v4f*)(t_p + off.w + s0);
        v4f tv[4];
        tv[0] = (v4f){t0.x, t1.x, t2.x, t3.x};
        tv[1] = (v4f){t0.y, t1.y, t2.y, t3.y};
        tv[2] = (v4f){t0.z, t1.z, t2.z, t3.z};
        tv[3] = (v4f){t0.w, t1.w, t2.w, t3.w};

        const size_t base = ((size_t)b * HW + s0) * C + c0;
        const float* __restrict__ xq = x + base;
        const float* __restrict__ cp = ctp + (size_t)s0 * C + c0;
        float* __restrict__ out_m = out + base;
        float* __restrict__ out_x = out + plane + base;
        float* __restrict__ out_t = out + 2 * plane + base;

#pragma unroll
        for (int i = 0; i < 4; ++i) {
            v4f xv = *(const v4f*)(xq + (size_t)i * C);
            v4f ct = *(const v4f*)(cp + (size_t)i * C);
            v4f tt = tv[i];
            v4f m;
            m.x = fmaxf(xv.x * tt.x, 0.0f) * ct.x;
            m.y = fmaxf(xv.y * tt.y, 0.0f) * ct.y;
            m.z = fmaxf(xv.z * tt.z, 0.0f) * ct.z;
            m.w = fmaxf(xv.w * tt.w, 0.0f) * ct.w;
            __builtin_nontemporal_store(m,  (v4f*)(out_m + (size_t)i * C));
            __builtin_nontemporal_store(xv, (v4f*)(out_x + (size_t)i * C));
            __builtin_nontemporal_store(tt, (v4f*)(out_t + (size_t)i * C));
        }
    }
}

// ---------------------------------------------------------------------------
extern "C" void kernel_launch(void* const* d_in, const int* in_sizes, int n_in,
                              void* d_out, int out_size, void* d_ws, size_t ws_size,
                              hipStream_t stream) {
    const float* x    = (const float*)d_in[0];  // [B,H,W,C]
    const float* gt   = (const float*)d_in[1];  // [B,NCLS]
    const float* t_p  = (const float*)d_in[2];  // [15,15,H,W]
    const float* ctpl = (const float*)d_in[3];  // [NCLS,H,W,C]
    float* out = (float*)d_out;                 // [3, B,H,W,C] flat

    hipLaunchKernelGGL(fused_kernel,
                       dim3(4 * B), dim3(512), 0, stream,
                       x, gt, t_p, ctpl, out);
}

// Round 4
// 250.321 us; speedup vs baseline: 1.0884x; 1.0403x over previous
//
#include <hip/hip_runtime.h>

// Problem constants (from reference setup_inputs)
#define B    128
#define H    14
#define W    14
#define C    512
#define NCLS 200
#define HW   (H * W)          // 196
#define TP_DIM 15             // t_p is [15,15,14,14]
#define SENT_OFF ((14 * TP_DIM + 14) * HW)  // sentinel template row offset

typedef float  v4f __attribute__((ext_vector_type(4)));
typedef int    v4i __attribute__((ext_vector_type(4)));

// ---------------------------------------------------------------------------
// Fused kernel v4: LDS-staged template tile (kills divergent t_p gathers).
//
// Evidence: big-fill dispatch IDs are ≡ mod 7 across all rounds -> ONE 93 µs
// fill per iteration -> this kernel is ~160 µs, 4x its ~40 µs roofline, and
// occupancy doubling was null. The structure-invariant cost is phase 2's
// per-lane-random t_p gathers: 4 loads/unit, each wave-instruction touching
// up to 64 distinct cache lines, plus a 16-mov register transpose behind the
// gather latency.
//
// v4: after the argmax combine, cooperatively copy this block's 128 t_p rows
// (contiguous 784 B each, L2-resident) into LDS laid out [spatial][channel],
// in TWO spatial halves (quads 0..23, 24..48) so static LDS stays <= 64 KB
// (union-aliased with phase-1 scratch; 51.7 KB total -> 2 blocks/CU).
// Phase 2 then reads templates as aligned conflict-free ds_read_b128
// (contiguous across lanes) instead of 64-way-divergent global gathers.
//
// XCD swizzle: b = blockIdx&127, quarter = blockIdx>>7 -> the 4 quarter-
// blocks of batch b all have blockIdx ≡ b (mod 8) -> same XCD -> the 401 KB
// ctpl class row is fetched into one L2, not four.
// ---------------------------------------------------------------------------
__global__ __launch_bounds__(512) void fused_kernel(
        const float* __restrict__ x,
        const float* __restrict__ gt,
        const float* __restrict__ t_p,
        const float* __restrict__ ctpl,
        float*       __restrict__ out) {
    __shared__ union SMem {
        struct { v4f best[14][32]; v4i idx[14][32]; } ph1;  // 14,336 B
        float t_tile[100][128];                              // 51,200 B
    } smem;
    __shared__ int s_off[128];
    __shared__ int s_cls;

    const int tid     = threadIdx.x;
    const int b       = blockIdx.x & 127;   // XCD swizzle (see header)
    const int quarter = blockIdx.x >> 7;
    const int cg      = tid & 31;     // channel group (4 channels) 0..31
    const int sl      = tid >> 5;     // slice / quad-slot id 0..15
    const int c0      = quarter * 128 + cg * 4;   // global channel base
    const int cl      = cg * 4;                   // local channel base

    const float* __restrict__ xp = x + (size_t)b * HW * C + c0;

    // ---------------- Phase 1: argmaxes ------------------------------------
    if (sl < 14) {
        // spatial slice 14*sl .. 14*sl+13 for channels c0..c0+3
        const int sbeg = sl * 14;
        v4f best = *(const v4f*)(xp + (size_t)sbeg * C);
        v4i bidx = (v4i){sbeg, sbeg, sbeg, sbeg};
#pragma unroll
        for (int k = 1; k < 14; ++k) {
            const int s = sbeg + k;
            v4f v = *(const v4f*)(xp + (size_t)s * C);
            if (v.x > best.x) { best.x = v.x; bidx.x = s; }  // strict > = first occ.
            if (v.y > best.y) { best.y = v.y; bidx.y = s; }
            if (v.z > best.z) { best.z = v.z; bidx.z = s; }
            if (v.w > best.w) { best.w = v.w; bidx.w = s; }
        }
        smem.ph1.best[sl][cg] = best;
        smem.ph1.idx[sl][cg]  = bidx;
    } else {
        // wave 7 (tid 448..511): class argmax over gt[b], index-min tie-break
        const int lane = tid - 448;
        const float* __restrict__ g = gt + (size_t)b * NCLS;
        float gb = -__builtin_inff();
        int   gi = NCLS;
        for (int i = lane; i < NCLS; i += 64) {   // ascending per lane
            float v = g[i];
            if (v > gb) { gb = v; gi = i; }       // keeps smallest index
        }
#pragma unroll
        for (int d = 1; d < 64; d <<= 1) {
            float ov = __shfl_xor(gb, d);
            int   oi = __shfl_xor(gi, d);
            if (ov > gb || (ov == gb && oi < gi)) { gb = ov; gi = oi; }
        }
        if (lane == 0) s_cls = gi;
    }
    __syncthreads();

    // ---------------- Combine: fold 14 slices, compute t_p offsets ---------
    if (tid < 32) {
        v4f cb = smem.ph1.best[0][tid];
        v4i ci = smem.ph1.idx[0][tid];
#pragma unroll
        for (int k = 1; k < 14; ++k) {          // ascending s: '>' keeps first
            v4f p = smem.ph1.best[k][tid];
            v4i q = smem.ph1.idx[k][tid];
            if (p.x > cb.x) { cb.x = p.x; ci.x = q.x; }
            if (p.y > cb.y) { cb.y = p.y; ci.y = q.y; }
            if (p.z > cb.z) { cb.z = p.z; ci.z = q.z; }
            if (p.w > cb.w) { cb.w = p.w; ci.w = q.w; }
        }
        v4i o;
        o.x = (cb.x == 0.0f) ? SENT_OFF : ((ci.x / W) * TP_DIM + (ci.x % W)) * HW;
        o.y = (cb.y == 0.0f) ? SENT_OFF : ((ci.y / W) * TP_DIM + (ci.y % W)) * HW;
        o.z = (cb.z == 0.0f) ? SENT_OFF : ((ci.z / W) * TP_DIM + (ci.z % W)) * HW;
        o.w = (cb.w == 0.0f) ? SENT_OFF : ((ci.w / W) * TP_DIM + (ci.w % W)) * HW;
        *(v4i*)&s_off[tid * 4] = o;
    }
    __syncthreads();   // s_off visible; ph1 scratch dead -> t_tile may alias

    const int klass = s_cls;
    const size_t plane = (size_t)B * HW * C;
    const float* __restrict__ ctp = ctpl + (size_t)klass * HW * C;

    // stage: copy t_p rows (contiguous, L2-resident) into LDS [s][c_local].
    // thread t: local channel r = t>>2, v4f chunk ids j ≡ (t&3) mod 4.
    const int r = tid >> 2;
    const int p = tid & 3;
    const float* __restrict__ trow = t_p + s_off[r];

    auto stage = [&](int jbeg, int jend, int sbase) {
        for (int j = jbeg + p; j < jend; j += 4) {
            v4f v = *(const v4f*)(trow + j * 4);   // 16-B aligned (off%4==0)
            const int s = j * 4 - sbase;
            smem.t_tile[s + 0][r] = v.x;
            smem.t_tile[s + 1][r] = v.y;
            smem.t_tile[s + 2][r] = v.z;
            smem.t_tile[s + 3][r] = v.w;
        }
    };

    auto process_quad = [&](int q, int sbase) {
        const int s0 = q * 4;
        v4f tvv[4];
#pragma unroll
        for (int i = 0; i < 4; ++i)   // conflict-free: lanes contiguous in c
            tvv[i] = *(const v4f*)&smem.t_tile[s0 - sbase + i][cl];

        const size_t base = ((size_t)b * HW + s0) * C + c0;
        const float* __restrict__ xq = x + base;
        const float* __restrict__ cp = ctp + (size_t)s0 * C + c0;
        float* __restrict__ out_m = out + base;
        float* __restrict__ out_x = out + plane + base;
        float* __restrict__ out_t = out + 2 * plane + base;

#pragma unroll
        for (int i = 0; i < 4; ++i) {
            v4f xv = *(const v4f*)(xq + (size_t)i * C);
            v4f ct = *(const v4f*)(cp + (size_t)i * C);
            v4f tt = tvv[i];
            v4f m;
            m.x = fmaxf(xv.x * tt.x, 0.0f) * ct.x;
            m.y = fmaxf(xv.y * tt.y, 0.0f) * ct.y;
            m.z = fmaxf(xv.z * tt.z, 0.0f) * ct.z;
            m.w = fmaxf(xv.w * tt.w, 0.0f) * ct.w;
            __builtin_nontemporal_store(m,  (v4f*)(out_m + (size_t)i * C));
            __builtin_nontemporal_store(xv, (v4f*)(out_x + (size_t)i * C));
            __builtin_nontemporal_store(tt, (v4f*)(out_t + (size_t)i * C));
        }
    };

    // ---- half 0: quads 0..23 (spatial 0..95) ------------------------------
    stage(0, 24, 0);
    __syncthreads();
    process_quad(sl, 0);                       // q = 0..15
    if (sl < 8) process_quad(sl + 16, 0);      // q = 16..23
    __syncthreads();

    // ---- half 1: quads 24..48 (spatial 96..195) ---------------------------
    stage(24, 49, 96);
    __syncthreads();
    process_quad(24 + sl, 96);                 // q = 24..39
    if (sl <= 8) process_quad(40 + sl, 96);    // q = 40..48
}

// ---------------------------------------------------------------------------
extern "C" void kernel_launch(void* const* d_in, const int* in_sizes, int n_in,
                              void* d_out, int out_size, void* d_ws, size_t ws_size,
                              hipStream_t stream) {
    const float* x    = (const float*)d_in[0];  // [B,H,W,C]
    const float* gt   = (const float*)d_in[1];  // [B,NCLS]
    const float* t_p  = (const float*)d_in[2];  // [15,15,H,W]
    const float* ctpl = (const float*)d_in[3];  // [NCLS,H,W,C]
    float* out = (float*)d_out;                 // [3, B,H,W,C] flat

    hipLaunchKernelGGL(fused_kernel,
                       dim3(4 * B), dim3(512), 0, stream,
                       x, gt, t_p, ctpl, out);
}